// Round 5
// baseline (210.861 us; speedup 1.0000x reference)
//
#include <hip/hip_runtime.h>

// HierarchicalRouter: x[16384,2048] fp32, group_gate_w[8,2048], expert_gate_w[64,2048]
// out = concat(valid_mask[16384,64] as 0/1 float, normalized_weights[16384,64])
//
// R9 = R8 minus the x LDS round-trip (LDS was the binding pipe: 132KB/chunk ~ 1580cy
// x 32 chunks ~ 21us of LDS serialization alone).
//  * x B-fragments now load DIRECT from global into named 2-deep prefetch regs
//    (xA/xB float4 pairs, ~2 chunks ~ 1300cy in flight > 900cy HBM latency), h/l
//    split in-reg at use (~32 VALU, hides under LDS+MFMA). No x ds_write/ds_read,
//    no x swizzle. LDS traffic/chunk: 132KB -> 100KB (W reads 80 + W writes 20).
//  * W path byte-identical to R8: prep-presplit chunk-contiguous fragment blobs
//    ([ks(64)][g(5)][pl(2)][slot(64)][j(8)] halfs), router stages 20480B/chunk as a
//    dense linear 16B/lane copy, double-buffered, loads fly over compute and drain
//    at the commit in the same chunk (~600cy > L2 ~250cy).
//  * router (256x512): 64 tokens/block, 32 chunks of 64k. Wave w = (tt=w>>1 token-
//    tile, s2=w&1 k-half of chunk); per chunk: 10 ds_read_b128 (W), 2 global dwordx4
//    (x), 15 mfma_f32_16x16x32_f16. logit = accH + accC/2048 (proven exact-split).
//  * Epilogue unchanged from R8: 2-way K-reduce, softmax 8 tok/wave (proven fp32),
//    coalesced stores. LDS 74752B.

#define NT 16384
#define NE 2048
#define NTH 512
#define NBLK 256
#define NCHUNK 32
#define WCH 20480
#define LDS_BYTES 74752

typedef _Float16 v8h __attribute__((ext_vector_type(8)));
typedef float    v4f __attribute__((ext_vector_type(4)));

__global__ __launch_bounds__(256, 1)
void prep(const float* __restrict__ gw, const float* __restrict__ ew,
          _Float16* __restrict__ wf)
{
    const int t = blockIdx.x * 256 + threadIdx.x;   // 0..163839: one (ks,g,slot,j)
    const int j    = t & 7;
    const int sl   = (t >> 3) & 63;                 // slot = q*16 + m (A-fragment lane)
    const int rest = t >> 9;                        // 0..319
    const int g    = rest % 5;
    const int ks   = rest / 5;                      // 0..63 (32-float k-step)
    const int m = sl & 15, q = sl >> 4;
    const int gate = g * 16 + m;
    const int k = ks * 32 + q * 8 + j;
    float v = 0.f;
    if (gate < 64)      v = ew[gate * NE + k];
    else if (gate < 72) v = gw[(gate - 64) * NE + k];
    const _Float16 h = (_Float16)v;
    const int o = (((ks * 5 + g) * 2) * 64 + sl) * 8 + j;   // pl=0 plane
    wf[o]       = h;
    wf[o + 512] = (_Float16)((v - (float)h) * 2048.0f);     // pl=1 plane (+64 slots)
}

__global__ __launch_bounds__(NTH, 2)
void router(const float* __restrict__ x, const _Float16* __restrict__ wf,
            float* __restrict__ out)
{
    __shared__ __align__(16) char sm[LDS_BYTES];
    const int tid  = threadIdx.x;
    const int lane = tid & 63;
    const int w    = tid >> 6;
    const int tt   = w >> 1, s2 = w & 1;
    const int t0   = blockIdx.x * 64;

    // ---- x B-fragment source: token = lane&15 of tile tt, k = c*64 + s2*32 + (lane>>4)*8 ----
    const float* xq = x + (size_t)(t0 + tt * 16 + (lane & 15)) * NE
                    + s2 * 32 + (lane >> 4) * 8;

    // ---- W copy: 1280 x 16B per chunk, dense linear (tid + i*512 slots) ----
    uint4 wr0, wr1, wr2;
    auto wload = [&](int c) {
        const char* src = (const char*)wf + (size_t)c * WCH;
        wr0 = *(const uint4*)(src + (0 * 512 + tid) * 16);
        wr1 = *(const uint4*)(src + (1 * 512 + tid) * 16);
        if (tid < 256) wr2 = *(const uint4*)(src + (1024 + tid) * 16);
    };
    auto wcommit = [&](int buf) {
        char* dst = sm + buf * WCH;
        *(uint4*)(dst + (0 * 512 + tid) * 16) = wr0;
        *(uint4*)(dst + (1 * 512 + tid) * 16) = wr1;
        if (tid < 256) *(uint4*)(dst + (1024 + tid) * 16) = wr2;
    };

    v4f accH[5], accC[5];
    #pragma unroll
    for (int g = 0; g < 5; ++g) { accH[g] = (v4f)(0.f); accC[g] = (v4f)(0.f); }

    const int wrd = s2 * 10240 + lane * 16;     // k-half base + fragment slot

    auto xload_to = [&](int c, float4& r0, float4& r1) {
        const float* p = xq + c * 64;
        r0 = *(const float4*)(p);
        r1 = *(const float4*)(p + 4);
    };

    auto mfma_block = [&](int P, const v8h& Bh, const v8h& Bl) {
        const char* wb = sm + P * WCH;
        #pragma unroll
        for (int g = 0; g < 5; ++g) {
            const char* wpg = wb + wrd + g * 2048;
            const v8h Ah = *(const v8h*)(wpg);
            const v8h Al = *(const v8h*)(wpg + 1024);
            accH[g] = __builtin_amdgcn_mfma_f32_16x16x32_f16(Ah, Bh, accH[g], 0, 0, 0);
            accC[g] = __builtin_amdgcn_mfma_f32_16x16x32_f16(Ah, Bl, accC[g], 0, 0, 0);
            accC[g] = __builtin_amdgcn_mfma_f32_16x16x32_f16(Al, Bh, accC[g], 0, 0, 0);
        }
    };

    // step(c): barrier -> wload(c+1) -> split regs(c) -> xload(c+2) into same regs
    //          -> MFMA on buf[P] -> wcommit(c+1). Named regs only (rule #20).
    auto step = [&](int c, int P, float4& cur0, float4& cur1) {
        __syncthreads();                        // buf[P] published
        if (c + 1 < NCHUNK) wload(c + 1);
        v8h Bh, Bl;
        {
            const float v[8] = {cur0.x, cur0.y, cur0.z, cur0.w,
                                cur1.x, cur1.y, cur1.z, cur1.w};
            #pragma unroll
            for (int j = 0; j < 8; ++j) {
                const _Float16 hh = (_Float16)v[j];
                Bh[j] = hh;
                Bl[j] = (_Float16)((v[j] - (float)hh) * 2048.0f);
            }
        }
        if (c + 2 < NCHUNK) xload_to(c + 2, cur0, cur1);   // WAR after split
        mfma_block(P, Bh, Bl);
        if (c + 1 < NCHUNK) wcommit(1 - P);
    };

    // named 2-deep x prefetch: even chunks in A, odd in B
    float4 xA0, xA1, xB0, xB1;

    // ---- prologue ----
    wload(0);
    xload_to(0, xA0, xA1);
    xload_to(1, xB0, xB1);
    wcommit(0);

    #pragma unroll 1
    for (int cc = 0; cc < NCHUNK; cc += 2) {
        step(cc,     0, xA0, xA1);      // computes chunk cc,   loads cc+2 into A
        step(cc + 1, 1, xB0, xB1);      // computes chunk cc+1, loads cc+3 into B
    }
    __syncthreads();

    // ---- exact recombine + 2-way K-reduce (across s2 halves) ----
    float part[5][4];
    #pragma unroll
    for (int g = 0; g < 5; ++g)
        #pragma unroll
        for (int r = 0; r < 4; ++r)
            part[g][r] = accH[g][r] + accC[g][r] * (1.0f / 2048.0f);

    float* red = (float*)sm;                       // [tt][g][r][lane] = 20480 B
    if (s2 == 1) {
        #pragma unroll
        for (int g = 0; g < 5; ++g)
            #pragma unroll
            for (int r = 0; r < 4; ++r)
                red[((tt * 5 + g) * 4 + r) * 64 + lane] = part[g][r];
    }
    __syncthreads();
    float* la = (float*)(sm + 20480);              // [64 tokens][84]
    if (s2 == 0) {
        #pragma unroll
        for (int g = 0; g < 5; ++g)
            #pragma unroll
            for (int r = 0; r < 4; ++r) {
                const float v = part[g][r] + red[((tt * 5 + g) * 4 + r) * 64 + lane];
                const int gate  = g * 16 + (lane >> 4) * 4 + r;   // D row = gate
                const int token = tt * 16 + (lane & 15);          // D col = token
                la[token * 84 + gate] = v;
            }
    }
    __syncthreads();

    // ---- per-token dual softmax + hierarchical mask (proven fp32), 8 tok/wave ----
    if (lane < 8) {
        const int token = w * 8 + lane;
        const float* lg = la + token * 84;          // [0..63]=experts, [64..71]=groups
        float* M  = (float*)(sm + 41984) + token * 64;
        float* Wn = (float*)(sm + 58368) + token * 64;

        float gpb[8];
        float gmax = lg[64];
        #pragma unroll
        for (int g = 1; g < 8; ++g) gmax = fmaxf(gmax, lg[64 + g]);
        float gsum = 0.f;
        #pragma unroll
        for (int g = 0; g < 8; ++g) { gpb[g] = __expf(lg[64 + g] - gmax); gsum += gpb[g]; }
        const float ginv = 1.f / gsum;

        float sel[64];
        float wsum = 0.f;
        #pragma unroll
        for (int g = 0; g < 8; ++g) {
            const float gp_ = gpb[g] * ginv;
            float emax = lg[g * 8];
            #pragma unroll
            for (int j = 1; j < 8; ++j) emax = fmaxf(emax, lg[g * 8 + j]);
            float ep[8]; float esum = 0.f;
            #pragma unroll
            for (int j = 0; j < 8; ++j) { ep[j] = __expf(lg[g * 8 + j] - emax); esum += ep[j]; }
            const float einv = 1.f / esum;
            const bool gm = gp_ >= 0.125f;
            #pragma unroll
            for (int j = 0; j < 8; ++j) {
                const float pe = ep[j] * einv;
                const bool v = gm && (pe >= 0.125f);
                const float ww = v ? gp_ * pe : 0.f;
                M[g * 8 + j] = v ? 1.f : 0.f;
                sel[g * 8 + j] = ww;
                wsum += ww;
            }
        }
        const float inv = 1.f / fmaxf(wsum, 1e-9f);
        #pragma unroll
        for (int e = 0; e < 64; ++e) Wn[e] = sel[e] * inv;
    }
    __syncthreads();

    // ---- coalesced stores: 64 tokens x 64 = 1024 float4 per tensor ----
    const float4* M4 = (const float4*)(sm + 41984);
    const float4* W4 = (const float4*)(sm + 58368);
    float4* o0 = (float4*)(out + (size_t)t0 * 64);
    float4* o1 = (float4*)(out + (size_t)NT * 64 + (size_t)t0 * 64);
    o0[tid]       = M4[tid];
    o0[tid + 512] = M4[tid + 512];
    o1[tid]       = W4[tid];
    o1[tid + 512] = W4[tid + 512];
}

extern "C" void kernel_launch(void* const* d_in, const int* in_sizes, int n_in,
                              void* d_out, int out_size, void* d_ws, size_t ws_size,
                              hipStream_t stream) {
    const float* x  = (const float*)d_in[0];
    const float* gw = (const float*)d_in[1];
    const float* ew = (const float*)d_in[2];
    float* out = (float*)d_out;
    _Float16* wf = (_Float16*)d_ws;
    (void)ws_size; (void)in_sizes; (void)n_in; (void)out_size;

    prep<<<dim3(640), dim3(256), 0, stream>>>(gw, ew, wf);
    router<<<dim3(NBLK), dim3(NTH), 0, stream>>>(x, wf, out);
}

// Round 7
// 205.466 us; speedup vs baseline: 1.0263x; 1.0263x over previous
//
#include <hip/hip_runtime.h>

// HierarchicalRouter: x[16384,2048] fp32, group_gate_w[8,2048], expert_gate_w[64,2048]
// out = concat(valid_mask[16384,64] as 0/1 float, normalized_weights[16384,64])
//
// R11 = R10 with the W-fragment read bug fixed: R10 read A-fragments at
// (wb + g*2048) with NO lane*16 slot offset -> every lane got slot 0 -> absmax 1.0.
// Correct read = sm + P*WCH + w*KSB + lane*16 + g*2048 (+1024 for l-plane), matching
// prep layout ks*10240 + g*2048 + pl*1024 + slot*16 + j*2 and the glds identity copy
// (HW writes lane i at lds_base + i*16).
//
// Structure (unchanged from R10):
//   * 512 blocks x 256 thr (4 waves), 32 tokens/block, LDS 81920B -> EXACTLY
//     2 blocks/CU: two independent barrier pipelines interleave, so one block's
//     vmcnt(0) barrier-drain overlaps the other block's compute/loads.
//   * W staging via __builtin_amdgcn_global_load_lds width=16 (dense presplit blob
//     -> linear LDS): no staging VGPRs, no commit VALU. Double-buffered 40960B.
//   * Wave w = ks-within-chunk (K split 4-way, 32 k each); each wave processes BOTH
//     16-token tiles -> 10 ds_read_b128 feed 30 MFMAs per chunk.
//   * x B-fragments direct from global, named 2-deep register prefetch (rule #20),
//     f16 h/l split in-reg. logit = accH + accC/2048 (proven exact-split).
//   * Epilogue: 4-way K-reduce, softmax 8 tok/wave (proven fp32), coalesced stores.

#define NT 16384
#define NE 2048
#define NTH 256
#define NBLK 512
#define NCHUNK 16
#define KSB 10240
#define WCH 40960
#define LDS_BYTES 81920

typedef _Float16 v8h __attribute__((ext_vector_type(8)));
typedef float    v4f __attribute__((ext_vector_type(4)));

__global__ __launch_bounds__(256, 1)
void prep(const float* __restrict__ gw, const float* __restrict__ ew,
          _Float16* __restrict__ wf)
{
    const int t = blockIdx.x * 256 + threadIdx.x;   // 0..163839: one (ks,g,slot,j)
    const int j    = t & 7;
    const int sl   = (t >> 3) & 63;                 // slot = q*16 + m (A-fragment lane)
    const int rest = t >> 9;                        // 0..319
    const int g    = rest % 5;
    const int ks   = rest / 5;                      // 0..63 (32-float k-step)
    const int m = sl & 15, q = sl >> 4;
    const int gate = g * 16 + m;
    const int k = ks * 32 + q * 8 + j;
    float v = 0.f;
    if (gate < 64)      v = ew[gate * NE + k];
    else if (gate < 72) v = gw[(gate - 64) * NE + k];
    const _Float16 h = (_Float16)v;
    const int o = (((ks * 5 + g) * 2) * 64 + sl) * 8 + j;   // pl=0 plane
    wf[o]       = h;
    wf[o + 512] = (_Float16)((v - (float)h) * 2048.0f);     // pl=1 plane (+64 slots)
}

__global__ __launch_bounds__(NTH, 2)
void router(const float* __restrict__ x, const _Float16* __restrict__ wf,
            float* __restrict__ out)
{
    __shared__ __align__(16) char sm[LDS_BYTES];
    const int tid  = threadIdx.x;
    const int lane = tid & 63;
    const int w    = tid >> 6;                 // ks-within-chunk 0..3
    const int t0   = blockIdx.x * 32;

    // ---- x B-fragment sources (token = lane&15 + 16*tile, k = c*128 + w*32 + (lane>>4)*8) ----
    const float* xq0 = x + (size_t)(t0 + (lane & 15)) * NE + w * 32 + (lane >> 4) * 8;
    const float* xq1 = xq0 + (size_t)16 * NE;

    // ---- W staging: global_load_lds, 10 x 1KB wave-issues per chunk ----
    auto stage = [&](int c, int buf) {
        const char* src = (const char*)wf + (size_t)c * WCH + w * KSB + lane * 16;
        char* dst = sm + buf * WCH + w * KSB;              // wave-uniform base
        #pragma unroll
        for (int i = 0; i < 10; ++i)
            __builtin_amdgcn_global_load_lds(
                (const __attribute__((address_space(1))) char*)(src + i * 1024),
                (__attribute__((address_space(3))) char*)(dst + i * 1024),
                16, 0, 0);
    };

    auto split8 = [](const float4& a, const float4& b, v8h& h, v8h& l) {
        const float v[8] = {a.x, a.y, a.z, a.w, b.x, b.y, b.z, b.w};
        #pragma unroll
        for (int j = 0; j < 8; ++j) {
            const _Float16 hh = (_Float16)v[j];
            h[j] = hh;
            l[j] = (_Float16)((v[j] - (float)hh) * 2048.0f);
        }
    };

    v4f accH0[5], accC0[5], accH1[5], accC1[5];
    #pragma unroll
    for (int g = 0; g < 5; ++g) {
        accH0[g] = (v4f)(0.f); accC0[g] = (v4f)(0.f);
        accH1[g] = (v4f)(0.f); accC1[g] = (v4f)(0.f);
    }

    auto xload = [&](int c, float4& a0, float4& a1, float4& b0, float4& b1) {
        const float* p0 = xq0 + c * 128;
        const float* p1 = xq1 + c * 128;
        a0 = *(const float4*)(p0); a1 = *(const float4*)(p0 + 4);
        b0 = *(const float4*)(p1); b1 = *(const float4*)(p1 + 4);
    };

    // step(c): barrier(publish buf P; drain glds) -> issue glds(c+1) -> split x(c)
    //          -> issue x loads(c+2) into same named regs (WAR) -> 10 ds_read + 30 MFMA
    auto step = [&](int c, int P, float4& c00, float4& c01, float4& c10, float4& c11) {
        __syncthreads();                        // buf P published (vmcnt(0) drains glds)
        if (c + 1 < NCHUNK) stage(c + 1, 1 - P);
        v8h Bh0, Bl0, Bh1, Bl1;
        split8(c00, c01, Bh0, Bl0);
        split8(c10, c11, Bh1, Bl1);
        if (c + 2 < NCHUNK) xload(c + 2, c00, c01, c10, c11);
        const char* wb = sm + P * WCH + w * KSB + lane * 16;   // <-- fixed: +lane*16
        #pragma unroll
        for (int g = 0; g < 5; ++g) {
            const v8h Ah = *(const v8h*)(wb + g * 2048);
            const v8h Al = *(const v8h*)(wb + g * 2048 + 1024);
            accH0[g] = __builtin_amdgcn_mfma_f32_16x16x32_f16(Ah, Bh0, accH0[g], 0, 0, 0);
            accC0[g] = __builtin_amdgcn_mfma_f32_16x16x32_f16(Ah, Bl0, accC0[g], 0, 0, 0);
            accC0[g] = __builtin_amdgcn_mfma_f32_16x16x32_f16(Al, Bh0, accC0[g], 0, 0, 0);
            accH1[g] = __builtin_amdgcn_mfma_f32_16x16x32_f16(Ah, Bh1, accH1[g], 0, 0, 0);
            accC1[g] = __builtin_amdgcn_mfma_f32_16x16x32_f16(Ah, Bl1, accC1[g], 0, 0, 0);
            accC1[g] = __builtin_amdgcn_mfma_f32_16x16x32_f16(Al, Bh1, accC1[g], 0, 0, 0);
        }
    };

    // named 2-deep x prefetch: even chunks in A, odd in B (rule #20)
    float4 xA00, xA01, xA10, xA11, xB00, xB01, xB10, xB11;

    // ---- prologue ----
    stage(0, 0);
    xload(0, xA00, xA01, xA10, xA11);
    xload(1, xB00, xB01, xB10, xB11);

    #pragma unroll 1
    for (int cc = 0; cc < NCHUNK; cc += 2) {
        step(cc,     0, xA00, xA01, xA10, xA11);
        step(cc + 1, 1, xB00, xB01, xB10, xB11);
    }
    __syncthreads();                            // all ds_reads done; sm reusable

    // ---- exact recombine + 4-way K-reduce (across the 4 ks-waves) ----
    float part[2][5][4];
    #pragma unroll
    for (int g = 0; g < 5; ++g)
        #pragma unroll
        for (int r = 0; r < 4; ++r) {
            part[0][g][r] = accH0[g][r] + accC0[g][r] * (1.0f / 2048.0f);
            part[1][g][r] = accH1[g][r] + accC1[g][r] * (1.0f / 2048.0f);
        }

    float* red = (float*)sm;                    // [w-1][tile][g][r][lane] = 30720 B
    if (w > 0) {
        #pragma unroll
        for (int t = 0; t < 2; ++t)
            #pragma unroll
            for (int g = 0; g < 5; ++g)
                #pragma unroll
                for (int r = 0; r < 4; ++r)
                    red[((((w - 1) * 2 + t) * 5 + g) * 4 + r) * 64 + lane] = part[t][g][r];
    }
    __syncthreads();
    float* la = (float*)(sm + 30720);           // [32 tokens][84]
    if (w == 0) {
        #pragma unroll
        for (int t = 0; t < 2; ++t)
            #pragma unroll
            for (int g = 0; g < 5; ++g)
                #pragma unroll
                for (int r = 0; r < 4; ++r) {
                    const float v = part[t][g][r]
                        + red[(((0 * 2 + t) * 5 + g) * 4 + r) * 64 + lane]
                        + red[(((1 * 2 + t) * 5 + g) * 4 + r) * 64 + lane]
                        + red[(((2 * 2 + t) * 5 + g) * 4 + r) * 64 + lane];
                    const int gate  = g * 16 + (lane >> 4) * 4 + r;   // D row = gate
                    const int token = t * 16 + (lane & 15);           // D col = token
                    la[token * 84 + gate] = v;
                }
    }
    __syncthreads();

    // ---- per-token dual softmax + hierarchical mask (proven fp32), 8 tok/wave ----
    if (lane < 8) {
        const int token = w * 8 + lane;
        const float* lg = la + token * 84;      // [0..63]=experts, [64..71]=groups
        float* M  = (float*)(sm + 41472) + token * 64;
        float* Wn = (float*)(sm + 49664) + token * 64;

        float gpb[8];
        float gmax = lg[64];
        #pragma unroll
        for (int g = 1; g < 8; ++g) gmax = fmaxf(gmax, lg[64 + g]);
        float gsum = 0.f;
        #pragma unroll
        for (int g = 0; g < 8; ++g) { gpb[g] = __expf(lg[64 + g] - gmax); gsum += gpb[g]; }
        const float ginv = 1.f / gsum;

        float sel[64];
        float wsum = 0.f;
        #pragma unroll
        for (int g = 0; g < 8; ++g) {
            const float gp_ = gpb[g] * ginv;
            float emax = lg[g * 8];
            #pragma unroll
            for (int j = 1; j < 8; ++j) emax = fmaxf(emax, lg[g * 8 + j]);
            float ep[8]; float esum = 0.f;
            #pragma unroll
            for (int j = 0; j < 8; ++j) { ep[j] = __expf(lg[g * 8 + j] - emax); esum += ep[j]; }
            const float einv = 1.f / esum;
            const bool gm = gp_ >= 0.125f;
            #pragma unroll
            for (int j = 0; j < 8; ++j) {
                const float pe = ep[j] * einv;
                const bool v = gm && (pe >= 0.125f);
                const float ww = v ? gp_ * pe : 0.f;
                M[g * 8 + j] = v ? 1.f : 0.f;
                sel[g * 8 + j] = ww;
                wsum += ww;
            }
        }
        const float inv = 1.f / fmaxf(wsum, 1e-9f);
        #pragma unroll
        for (int e = 0; e < 64; ++e) Wn[e] = sel[e] * inv;
    }
    __syncthreads();

    // ---- coalesced stores: 32 tokens x 64 = 512 float4 per tensor ----
    const float4* M4 = (const float4*)(sm + 41472);
    const float4* W4 = (const float4*)(sm + 49664);
    float4* o0 = (float4*)(out + (size_t)t0 * 64);
    float4* o1 = (float4*)(out + (size_t)NT * 64 + (size_t)t0 * 64);
    o0[tid]       = M4[tid];
    o0[tid + 256] = M4[tid + 256];
    o1[tid]       = W4[tid];
    o1[tid + 256] = W4[tid + 256];
}

extern "C" void kernel_launch(void* const* d_in, const int* in_sizes, int n_in,
                              void* d_out, int out_size, void* d_ws, size_t ws_size,
                              hipStream_t stream) {
    const float* x  = (const float*)d_in[0];
    const float* gw = (const float*)d_in[1];
    const float* ew = (const float*)d_in[2];
    float* out = (float*)d_out;
    _Float16* wf = (_Float16*)d_ws;
    (void)ws_size; (void)in_sizes; (void)n_in; (void)out_size;

    prep<<<dim3(640), dim3(256), 0, stream>>>(gw, ew, wf);
    router<<<dim3(NBLK), dim3(NTH), 0, stream>>>(x, wf, out);
}